// Round 3
// baseline (327.010 us; speedup 1.0000x reference)
//
#include <hip/hip_runtime.h>
#include <stdint.h>

// Problem constants
#define B_   2
#define T_   4096
#define C_   768
#define H_   12
#define D_   64
#define BH_  24      // B_*H_
#define M_   8192    // B_*T_
#define K_   768
#define N1_  2304    // 3*C_

#define NEG_BIG (-1.0e30f)

typedef short bf16x8 __attribute__((ext_vector_type(8)));
typedef float f32x4  __attribute__((ext_vector_type(4)));
typedef float f32x16 __attribute__((ext_vector_type(16)));
typedef uint32_t u32x4 __attribute__((ext_vector_type(4)));

typedef const __attribute__((address_space(1))) void* as1cv;
typedef __attribute__((address_space(3))) void*       as3v;

__device__ __forceinline__ void gload_lds16(const void* g, void* l) {
  __builtin_amdgcn_global_load_lds((as1cv)g, (as3v)l, 16, 0, 0);
}

// fp32 -> bf16 bits, round-to-nearest-even
__device__ __forceinline__ unsigned short f2bf(float f) {
  uint32_t x = __builtin_bit_cast(uint32_t, f);
  uint32_t r = (x + 0x7fffu + ((x >> 16) & 1u)) >> 16;
  return (unsigned short)r;
}

__device__ __forceinline__ uint32_t pk2bf(float lo, float hi) {
  return ((uint32_t)f2bf(hi) << 16) | (uint32_t)f2bf(lo);
}

// ---------------------------------------------------------------- cast x -> bf16
__global__ void cast_kernel(const float* __restrict__ in, unsigned short* __restrict__ out, int n4) {
  int idx = blockIdx.x * blockDim.x + threadIdx.x;
  int stride = gridDim.x * blockDim.x;
  for (int i = idx; i < n4; i += stride) {
    float4 v = reinterpret_cast<const float4*>(in)[i];
    ushort4 o;
    o.x = f2bf(v.x); o.y = f2bf(v.y); o.z = f2bf(v.z); o.w = f2bf(v.w);
    reinterpret_cast<ushort4*>(out)[i] = o;
  }
}

// ------------------------------------------- transpose + cast: in[K][N] -> out[N][K] bf16
__global__ void transpose_cast(const float* __restrict__ in, unsigned short* __restrict__ out,
                               int K, int N) {
  __shared__ float tile[32][33];
  const int tx = threadIdx.x, ty = threadIdx.y;
  const int n = blockIdx.x * 32 + tx;
  #pragma unroll
  for (int r = 0; r < 4; ++r) {
    int k = blockIdx.y * 32 + ty + r * 8;
    tile[ty + r * 8][tx] = in[(size_t)k * N + n];
  }
  __syncthreads();
  const int k = blockIdx.y * 32 + tx;
  #pragma unroll
  for (int r = 0; r < 4; ++r) {
    int nn = blockIdx.x * 32 + ty + r * 8;
    out[(size_t)nn * K + k] = f2bf(tile[tx][ty + r * 8]);
  }
}

// ---------------------------------------------------------------- GEMM (m97-like)
// C[M][N] = A[M][768] * BT[N][768]^T + bias
// MODE 0: scatter epilogue -> Q (x0.125), K as [BH][T][D], V transposed to [BH][D][T], bf16
// MODE 1: plain fp32 store to fo[M][768]
template <int MODE>
__global__ __launch_bounds__(256) void gemm_kernel(
    const unsigned short* __restrict__ A, const unsigned short* __restrict__ BT,
    const float* __restrict__ bias,
    unsigned short* __restrict__ o0, unsigned short* __restrict__ o1,
    unsigned short* __restrict__ o2, float* __restrict__ fo) {
  __shared__ __align__(16) unsigned short Al[128 * 32];
  __shared__ __align__(16) unsigned short Bl[128 * 32];
  const int tid = threadIdx.x;
  const int w = tid >> 6, lane = tid & 63;
  const int g = lane >> 4, c16 = lane & 15;
  const int wr = w >> 1, wc = w & 1;
  const int m0 = blockIdx.x * 128, n0 = blockIdx.y * 128;

  f32x4 acc[4][4] = {};

  for (int k0 = 0; k0 < K_; k0 += 32) {
    __syncthreads();
    #pragma unroll
    for (int q = 0; q < 2; ++q) {
      const int ch = (w * 2 + q) * 64 + lane;     // 0..511
      const int row = ch >> 2, kb = ch & 3;       // 128 rows x 4 x 16B
      gload_lds16(A  + (size_t)(m0 + row) * K_ + k0 + kb * 8, &Al[(w * 2 + q) * 512]);
      gload_lds16(BT + (size_t)(n0 + row) * K_ + k0 + kb * 8, &Bl[(w * 2 + q) * 512]);
    }
    __syncthreads();
    bf16x8 af[4], bfr[4];
    #pragma unroll
    for (int i = 0; i < 4; ++i) {
      af[i]  = *reinterpret_cast<const bf16x8*>(&Al[(wr * 64 + i * 16 + c16) * 32 + g * 8]);
      bfr[i] = *reinterpret_cast<const bf16x8*>(&Bl[(wc * 64 + i * 16 + c16) * 32 + g * 8]);
    }
    #pragma unroll
    for (int i = 0; i < 4; ++i)
      #pragma unroll
      for (int j = 0; j < 4; ++j)
        acc[i][j] = __builtin_amdgcn_mfma_f32_16x16x32_bf16(af[i], bfr[j], acc[i][j], 0, 0, 0);
  }

  const int which = (MODE == 0) ? (n0 / 768) : 0;
  #pragma unroll
  for (int i = 0; i < 4; ++i) {
    const int mbase = m0 + wr * 64 + i * 16 + g * 4;
    #pragma unroll
    for (int j2 = 0; j2 < 4; ++j2) {
      const int n = n0 + wc * 64 + j2 * 16 + c16;
      const float bv = bias[n];
      #pragma unroll
      for (int j = 0; j < 4; ++j) {
        float v = acc[i][j2][j] + bv;
        const int mm = mbase + j;
        if constexpr (MODE == 0) {
          const int cc = n - which * 768;
          const int hh = cc >> 6, dd = cc & 63;
          const int bb = mm >> 12, tt = mm & 4095;
          const size_t bh = (size_t)bb * H_ + hh;
          if (which == 0)      o0[(bh * T_ + tt) * D_ + dd] = f2bf(v * 0.125f); // Q pre-scaled
          else if (which == 1) o1[(bh * T_ + tt) * D_ + dd] = f2bf(v);          // K
          else                 o2[(bh * D_ + dd) * T_ + tt] = f2bf(v);          // V^T
        } else {
          fo[(size_t)mm * 768 + n] = v;
        }
      }
    }
  }
}

// ---------------------------------------------------------------- flash attention
// 4 waves x 32 q-rows = 128 q-rows/block, KVBLK=64, 32x32x16 MFMA.
// Swapped QK^T (mfma(K,Q) -> S^T): lane owns ONE q-row (col = lane&31);
// softmax state is lane-local. PV as Y^T = V^T * P^T. P half-exchange via
// __shfl_xor(.,32)+select (verified ops only). All-finite math (mask = -1e30).
__global__ __launch_bounds__(256) void attn_kernel(
    const unsigned short* __restrict__ Qb, const unsigned short* __restrict__ Kb,
    const unsigned short* __restrict__ Vt, unsigned short* __restrict__ Yb) {
  __shared__ __align__(16) unsigned short KV[8192];  // K bytes [0,8192), V^T bytes [8192,16384)

  const int tid = threadIdx.x;
  const int w = tid >> 6, lane = tid & 63;
  const int q31 = lane & 31, hi = lane >> 5;
  const int bh = blockIdx.y;
  const int bb = bh / H_, hh = bh % H_;
  const int qb0 = ((int)gridDim.x - 1 - (int)blockIdx.x) * 128;  // long blocks first
  const int q0 = qb0 + w * 32;
  const int qg = q0 + q31;  // this lane's q row

  const size_t hoff = (size_t)bh * T_ * D_;
  const unsigned short* Qh = Qb + hoff;
  const unsigned short* Kh = Kb + hoff;
  const unsigned short* Vh = Vt + hoff;  // [64][4096]

  // Q fragments: B-operand, col = q31, k = s*16 + hi*8 + e
  bf16x8 qf[4];
  #pragma unroll
  for (int s = 0; s < 4; ++s)
    qf[s] = *reinterpret_cast<const bf16x8*>(&Qh[(size_t)qg * D_ + s * 16 + hi * 8]);

  // staging: thread covers linear chunk tid (K) / 256+tid etc.; row=chunk>>3, slot=chunk&7
  const int krow = tid >> 3;                            // 0..31 (+32 second call)
  const int cg   = (tid & 7) ^ (krow & 7);              // pre-swizzled source chunk
  const unsigned short* Ksrc = Kh + (size_t)krow * D_ + cg * 8;
  const unsigned short* Vsrc = Vh + (size_t)krow * T_ + cg * 8;

  // frag read addrs (bytes): row q31, chunk c = 2s+hi, swizzle ^(q31&7)
  int pa[4];
  #pragma unroll
  for (int s = 0; s < 4; ++s)
    pa[s] = q31 * 128 + (((2 * s + hi) ^ (q31 & 7)) << 4);
  const char* lds = (const char*)&KV[0];

  float mrun = NEG_BIG, lrun = 0.f;
  f32x16 y0 = {}, y1 = {};

  const int nt = (qb0 + 191) >> 6;

  for (int it = 0; it < nt; ++it) {
    const int kv0 = it << 6;
    __syncthreads();
    const unsigned short* kS = Ksrc + (size_t)kv0 * D_;
    const unsigned short* vS = Vsrc + kv0;
    gload_lds16(kS,                   &KV[w * 512]);
    gload_lds16(kS + 32 * D_,         &KV[2048 + w * 512]);
    gload_lds16(vS,                   &KV[4096 + w * 512]);
    gload_lds16(vS + (size_t)32 * T_, &KV[4096 + 2048 + w * 512]);
    __syncthreads();

    if (kv0 > q0 + 31) continue;  // wave-uniform causal skip (after barriers)

    // ---- S^T = K * Q^T : two 32x32 half-tiles (kv 0..31, 32..63)
    f32x16 s0 = {}, s1 = {};
    #pragma unroll
    for (int s = 0; s < 4; ++s) {
      bf16x8 kf0 = *reinterpret_cast<const bf16x8*>(lds + pa[s]);
      s0 = __builtin_amdgcn_mfma_f32_32x32x16_bf16(kf0, qf[s], s0, 0, 0, 0);
    }
    #pragma unroll
    for (int s = 0; s < 4; ++s) {
      bf16x8 kf1 = *reinterpret_cast<const bf16x8*>(lds + pa[s] + 4096);
      s1 = __builtin_amdgcn_mfma_f32_32x32x16_bf16(kf1, qf[s], s1, 0, 0, 0);
    }

    // ---- causal mask (finite sentinel); kv_local = (r&3)+8*(r>>2)+4*hi
    if (kv0 + 63 > q0) {
      #pragma unroll
      for (int r = 0; r < 16; ++r) {
        const int kvl = (r & 3) + 8 * (r >> 2) + 4 * hi;
        s0[r] = (kv0 + kvl > qg)      ? NEG_BIG : s0[r];
        s1[r] = (kv0 + 32 + kvl > qg) ? NEG_BIG : s1[r];
      }
    }

    // ---- column max: in-lane tree + cross-half merge (shfl_xor 32)
    float a[16];
    #pragma unroll
    for (int r = 0; r < 8; ++r) a[r] = fmaxf(s0[2 * r], s0[2 * r + 1]);
    #pragma unroll
    for (int r = 0; r < 8; ++r) a[8 + r] = fmaxf(s1[2 * r], s1[2 * r + 1]);
    #pragma unroll
    for (int st = 8; st > 0; st >>= 1)
      #pragma unroll
      for (int r = 0; r < 16; ++r) if (r < st) a[r] = fmaxf(a[r], a[r + st]);
    float tmax = a[0];
    tmax = fmaxf(tmax, __shfl_xor(tmax, 32));

    // ---- online rescale (every tile; lane-local)
    const float mnew = fmaxf(mrun, tmax);
    const float alpha = __expf(mrun - mnew);  // exp(-1e30) = 0 on first tile
    mrun = mnew;
    lrun *= alpha;
    #pragma unroll
    for (int r = 0; r < 16; ++r) { y0[r] *= alpha; y1[r] *= alpha; }

    // ---- P = exp(S - m)
    #pragma unroll
    for (int r = 0; r < 16; ++r) {
      s0[r] = __expf(s0[r] - mrun);
      s1[r] = __expf(s1[r] - mrun);
    }

    // ---- column sum: tree + merge
    #pragma unroll
    for (int r = 0; r < 8; ++r) a[r] = s0[2 * r] + s0[2 * r + 1];
    #pragma unroll
    for (int r = 0; r < 8; ++r) a[8 + r] = s1[2 * r] + s1[2 * r + 1];
    #pragma unroll
    for (int st = 8; st > 0; st >>= 1)
      #pragma unroll
      for (int r = 0; r < 16; ++r) if (r < st) a[r] = a[r] + a[r + st];
    float rsum = a[0];
    rsum += __shfl_xor(rsum, 32);
    lrun += rsum;

    // ---- P^T B-fragments via pk2bf + shfl_xor(32) + select.
    // Group a (a=0..3 per half): pair0 = pk(s[4a],s[4a+1]), pair1 = pk(s[4a+2],s[4a+3])
    // holds kv {8a..8a+3} on hi=0 lanes, {8a+4..8a+7} on hi=1 lanes.
    // pf[ks] (kv = ks*16 + hi*8 + e) from groups g=2ks, h=2ks+1:
    //   w0 = hi ? partner.h0 : g0 ; w1 = hi ? partner.h1 : g1
    //   w2 = hi ? h0 : partner.g0 ; w3 = hi ? h1 : partner.g1
    bf16x8 pf[4];
#define MK_PF(KS, SH, GA, HA)                                                 \
    {                                                                         \
      uint32_t g0 = pk2bf(SH[(GA)*4 + 0], SH[(GA)*4 + 1]);                    \
      uint32_t g1 = pk2bf(SH[(GA)*4 + 2], SH[(GA)*4 + 3]);                    \
      uint32_t h0 = pk2bf(SH[(HA)*4 + 0], SH[(HA)*4 + 1]);                    \
      uint32_t h1 = pk2bf(SH[(HA)*4 + 2], SH[(HA)*4 + 3]);                    \
      uint32_t sg0 = (uint32_t)__shfl_xor((int)g0, 32);                       \
      uint32_t sg1 = (uint32_t)__shfl_xor((int)g1, 32);                       \
      uint32_t sh0 = (uint32_t)__shfl_xor((int)h0, 32);                       \
      uint32_t sh1 = (uint32_t)__shfl_xor((int)h1, 32);                       \
      u32x4 t;                                                                \
      t[0] = hi ? sh0 : g0;                                                   \
      t[1] = hi ? sh1 : g1;                                                   \
      t[2] = hi ? h0 : sg0;                                                   \
      t[3] = hi ? h1 : sg1;                                                   \
      pf[KS] = __builtin_bit_cast(bf16x8, t);                                 \
    }
    MK_PF(0, s0, 0, 1)
    MK_PF(1, s0, 2, 3)
    MK_PF(2, s1, 0, 1)
    MK_PF(3, s1, 2, 3)
#undef MK_PF

    // ---- PV: Y^T += V^T * P^T  (A = V^T frag rows d, B = pf)
    #pragma unroll
    for (int ks = 0; ks < 4; ++ks) {
      bf16x8 vf0 = *reinterpret_cast<const bf16x8*>(lds + pa[ks] + 8192);
      y0 = __builtin_amdgcn_mfma_f32_32x32x16_bf16(vf0, pf[ks], y0, 0, 0, 0);
    }
    #pragma unroll
    for (int ks = 0; ks < 4; ++ks) {
      bf16x8 vf1 = *reinterpret_cast<const bf16x8*>(lds + pa[ks] + 12288);
      y1 = __builtin_amdgcn_mfma_f32_32x32x16_bf16(vf1, pf[ks], y1, 0, 0, 0);
    }
  }

  // ---- epilogue: y/l, store row qg (lane-local). y reg r -> d = (r&3)+8*(r>>2)+4*hi
  const float inv = 1.f / lrun;
  const size_t ro = ((size_t)bb * T_ + qg) * C_ + hh * D_;
  #pragma unroll
  for (int q2 = 0; q2 < 4; ++q2) {
    {
      uint32_t w0 = pk2bf(y0[q2 * 4 + 0] * inv, y0[q2 * 4 + 1] * inv);
      uint32_t w1 = pk2bf(y0[q2 * 4 + 2] * inv, y0[q2 * 4 + 3] * inv);
      uint2 pr = {w0, w1};
      *reinterpret_cast<uint2*>(&Yb[ro + q2 * 8 + hi * 4]) = pr;
    }
    {
      uint32_t w0 = pk2bf(y1[q2 * 4 + 0] * inv, y1[q2 * 4 + 1] * inv);
      uint32_t w1 = pk2bf(y1[q2 * 4 + 2] * inv, y1[q2 * 4 + 3] * inv);
      uint2 pr = {w0, w1};
      *reinterpret_cast<uint2*>(&Yb[ro + 32 + q2 * 8 + hi * 4]) = pr;
    }
  }
}

// ---------------------------------------------------------------- launch
extern "C" void kernel_launch(void* const* d_in, const int* in_sizes, int n_in,
                              void* d_out, int out_size, void* d_ws, size_t ws_size,
                              hipStream_t stream) {
  const float* x      = (const float*)d_in[0];
  const float* w_attn = (const float*)d_in[1];
  const float* b_attn = (const float*)d_in[2];
  const float* w_proj = (const float*)d_in[3];
  const float* b_proj = (const float*)d_in[4];
  float* out = (float*)d_out;

  char* ws = (char*)d_ws;
  size_t off = 0;
  auto alloc = [&](size_t bytes) -> void* {
    void* p = ws + off;
    off += (bytes + 255) & ~(size_t)255;
    return p;
  };
  unsigned short* xb  = (unsigned short*)alloc((size_t)M_ * K_ * 2);       // x bf16
  unsigned short* waT = (unsigned short*)alloc((size_t)N1_ * K_ * 2);      // w_attn^T bf16
  unsigned short* wpT = (unsigned short*)alloc((size_t)C_ * K_ * 2);       // w_proj^T bf16
  unsigned short* Qb  = (unsigned short*)alloc((size_t)BH_ * T_ * D_ * 2); // [BH][T][D]
  unsigned short* Kb  = (unsigned short*)alloc((size_t)BH_ * T_ * D_ * 2);
  unsigned short* Vt  = (unsigned short*)alloc((size_t)BH_ * D_ * T_ * 2); // [BH][D][T]
  unsigned short* Yb  = (unsigned short*)alloc((size_t)M_ * C_ * 2);       // attn out bf16

  cast_kernel<<<1024, 256, 0, stream>>>(x, xb, M_ * K_ / 4);
  transpose_cast<<<dim3(N1_ / 32, K_ / 32), dim3(32, 8), 0, stream>>>(w_attn, waT, K_, N1_);
  transpose_cast<<<dim3(C_ / 32, K_ / 32), dim3(32, 8), 0, stream>>>(w_proj, wpT, K_, C_);

  gemm_kernel<0><<<dim3(M_ / 128, N1_ / 128), 256, 0, stream>>>(
      xb, waT, b_attn, Qb, Kb, Vt, nullptr);

  attn_kernel<<<dim3(T_ / 128, BH_), 256, 0, stream>>>(Qb, Kb, Vt, Yb);

  gemm_kernel<1><<<dim3(M_ / 128, C_ / 128), 256, 0, stream>>>(
      Yb, wpT, b_proj, nullptr, nullptr, nullptr, out);
}